// Round 1
// baseline (576.047 us; speedup 1.0000x reference)
//
#include <hip/hip_runtime.h>
#include <hip/hip_bf16.h>
#include <math.h>

typedef __bf16 bf16_t;
typedef bf16_t bf16x8 __attribute__((ext_vector_type(8)));
typedef bf16_t bf16x4 __attribute__((ext_vector_type(4)));
typedef float  f32x4  __attribute__((ext_vector_type(4)));

#define MFMA_16x16x32_BF16(a, b, c) __builtin_amdgcn_mfma_f32_16x16x32_bf16((a), (b), (c), 0, 0, 0)

static constexpr int BB = 4, TT = 2048, CC = 1024, HH = 16, HD = 64;
static constexpr int C3 = 3 * CC;   // 3072
static constexpr int MM = BB * TT;  // 8192 rows

// ---------------- cast x (fp32) -> xb (bf16) ----------------
__global__ void cast_x_kernel(const float* __restrict__ x, bf16_t* __restrict__ xb, int n4) {
  int i = blockIdx.x * blockDim.x + threadIdx.x;
  if (i >= n4) return;
  float4 v = reinterpret_cast<const float4*>(x)[i];
  bf16x4 o;
  o[0] = (bf16_t)v.x; o[1] = (bf16_t)v.y; o[2] = (bf16_t)v.z; o[3] = (bf16_t)v.w;
  reinterpret_cast<bf16x4*>(xb)[i] = o;
}

// ------------- transpose+cast weights: in fp32 [R][Cn] -> out bf16 [Cn][R] -------------
__global__ void transpose_cast_kernel(const float* __restrict__ in, bf16_t* __restrict__ out,
                                      int R, int Cn) {
  __shared__ float tile[32][33];
  int c0 = blockIdx.x * 32, r0 = blockIdx.y * 32;
  int tx = threadIdx.x, ty = threadIdx.y;
#pragma unroll
  for (int i = 0; i < 4; ++i)
    tile[ty + 8 * i][tx] = in[(size_t)(r0 + ty + 8 * i) * Cn + c0 + tx];
  __syncthreads();
#pragma unroll
  for (int i = 0; i < 4; ++i)
    out[(size_t)(c0 + ty + 8 * i) * R + r0 + tx] = (bf16_t)tile[tx][ty + 8 * i];
}

// ------------- transpose V slice of qkv (bf16) -> vt [B][CC][TT] -------------
__global__ void transpose_v_kernel(const bf16_t* __restrict__ qkv, bf16_t* __restrict__ vt) {
  __shared__ bf16_t tile[32][33];
  int t0 = blockIdx.x * 32, c0 = blockIdx.y * 32, b = blockIdx.z;
  int tx = threadIdx.x, ty = threadIdx.y;
#pragma unroll
  for (int i = 0; i < 4; ++i)
    tile[ty + 8 * i][tx] = qkv[(size_t)(b * TT + t0 + ty + 8 * i) * C3 + 2048 + c0 + tx];
  __syncthreads();
#pragma unroll
  for (int i = 0; i < 4; ++i)
    vt[((size_t)b * CC + c0 + ty + 8 * i) * TT + t0 + tx] = tile[tx][ty + 8 * i];
}

// ------------- concat biases [bq | bkv] -> bias_cat[3072] -------------
__global__ void concat_bias_kernel(const float* __restrict__ bq, const float* __restrict__ bkv,
                                   float* __restrict__ dst) {
  int i = blockIdx.x * 256 + threadIdx.x;
  if (i >= 3072) return;
  const float* p = (i < 1024) ? (bq + i) : (bkv + i - 1024);
  dst[i] = *p;
}

// ---------------- GEMM: C[M,N] = A[M,K] * Bt[N,K]^T + bias ----------------
__device__ inline void store_out(float* p, float v)  { *p = v; }
__device__ inline void store_out(bf16_t* p, float v) { *p = (bf16_t)v; }

template <typename OutT>
__global__ __launch_bounds__(256) void gemm_kernel(
    const bf16_t* __restrict__ A, const bf16_t* __restrict__ Bt, OutT* __restrict__ C,
    const float* __restrict__ bias, int M, int N, int K) {
  __shared__ bf16_t As[128][40];  // +8 pad -> 2-way-only LDS conflicts
  __shared__ bf16_t Bs[128][40];
  const int tid = threadIdx.x;
  const int wid = tid >> 6, lane = tid & 63;
  const int lhi = lane >> 4, llo = lane & 15;
  const int wm = (wid >> 1) * 64, wn = (wid & 1) * 64;
  const int m0 = blockIdx.x * 128, n0 = blockIdx.y * 128;
  const int srow = tid >> 2, scol = (tid & 3) * 8;

  f32x4 acc[4][4] = {};
  const bf16_t* pa0 = A + (size_t)(m0 + srow) * K + scol;
  const bf16_t* pb0 = Bt + (size_t)(n0 + srow) * K + scol;

  for (int k0 = 0; k0 < K; k0 += 32) {
    __syncthreads();
    bf16x8 a0 = *(const bf16x8*)(pa0 + k0);
    bf16x8 a1 = *(const bf16x8*)(pa0 + (size_t)64 * K + k0);
    bf16x8 b0 = *(const bf16x8*)(pb0 + k0);
    bf16x8 b1 = *(const bf16x8*)(pb0 + (size_t)64 * K + k0);
    *(bf16x8*)&As[srow][scol]      = a0;
    *(bf16x8*)&As[srow + 64][scol] = a1;
    *(bf16x8*)&Bs[srow][scol]      = b0;
    *(bf16x8*)&Bs[srow + 64][scol] = b1;
    __syncthreads();
    bf16x8 af[4], bf[4];
#pragma unroll
    for (int mi = 0; mi < 4; ++mi) af[mi] = *(const bf16x8*)&As[wm + mi * 16 + llo][8 * lhi];
#pragma unroll
    for (int ni = 0; ni < 4; ++ni) bf[ni] = *(const bf16x8*)&Bs[wn + ni * 16 + llo][8 * lhi];
#pragma unroll
    for (int mi = 0; mi < 4; ++mi)
#pragma unroll
      for (int ni = 0; ni < 4; ++ni)
        acc[mi][ni] = MFMA_16x16x32_BF16(af[mi], bf[ni], acc[mi][ni]);
  }

#pragma unroll
  for (int mi = 0; mi < 4; ++mi) {
#pragma unroll
    for (int ni = 0; ni < 4; ++ni) {
      const int row = m0 + wm + mi * 16 + 4 * lhi;
      const int col = n0 + wn + ni * 16 + llo;
      const float bv = bias[col];
#pragma unroll
      for (int r = 0; r < 4; ++r)
        store_out(&C[(size_t)(row + r) * N + col], acc[mi][ni][r] + bv);
    }
  }
}

// ---------------- flash attention with ALiBi, causal ----------------
// grid (T/64, H, B), 256 threads = 4 waves; wave w owns q rows [qb+16w, qb+16w+16)
__global__ __launch_bounds__(256) void attn_kernel(
    const bf16_t* __restrict__ qkv,   // [B*T][3072]: q | k | v
    const bf16_t* __restrict__ vt,    // [B][CC][TT]
    const float* __restrict__ alibi_m,
    bf16_t* __restrict__ y) {         // [B*T][CC]
  __shared__ bf16_t Plds[4][16][32];
  const int b = blockIdx.z, h = blockIdx.y;
  const int qb = blockIdx.x * 64;
  const int tid = threadIdx.x, wid = tid >> 6, lane = tid & 63;
  const int lhi = lane >> 4, llo = lane & 15;
  const int q0 = qb + wid * 16;
  const float mh = alibi_m[h];

  // Q fragments (A operand): row = llo, k-offset 8*lhi; two d-halves
  const bf16_t* qp = qkv + (size_t)(b * TT + q0 + llo) * C3 + h * HD + 8 * lhi;
  const bf16x8 qf0 = *(const bf16x8*)qp;
  const bf16x8 qf1 = *(const bf16x8*)(qp + 32);

  const bf16_t* kbase = qkv + (size_t)b * TT * C3 + CC + h * HD + 8 * lhi;
  const bf16_t* vbase = vt + ((size_t)b * CC + h * HD) * TT;

  f32x4 acc[4] = {};
  float mrow[4] = {-INFINITY, -INFINITY, -INFINITY, -INFINITY};
  float lrow[4] = {0.f, 0.f, 0.f, 0.f};

  const int kv_end = qb + 64;
  for (int kv0 = 0; kv0 < kv_end; kv0 += 32) {
    // ---- S = Q K^T (two 16-col halves) ----
    const bf16_t* kp = kbase + (size_t)(kv0 + llo) * C3;
    bf16x8 k00 = *(const bf16x8*)kp;
    bf16x8 k01 = *(const bf16x8*)(kp + 32);
    bf16x8 k10 = *(const bf16x8*)(kp + (size_t)16 * C3);
    bf16x8 k11 = *(const bf16x8*)(kp + (size_t)16 * C3 + 32);
    f32x4 s0 = {}, s1 = {};
    s0 = MFMA_16x16x32_BF16(qf0, k00, s0);
    s0 = MFMA_16x16x32_BF16(qf1, k01, s0);
    s1 = MFMA_16x16x32_BF16(qf0, k10, s1);
    s1 = MFMA_16x16x32_BF16(qf1, k11, s1);

    // ---- online softmax (wave-parallel; rows live in regs r, cols across 16-lane group) ----
    const int j0 = kv0 + llo, j1 = j0 + 16;
    float alpha[4], p0[4], p1[4];
#pragma unroll
    for (int r = 0; r < 4; ++r) {
      const int i = q0 + 4 * lhi + r;
      float v0 = (j0 <= i) ? fmaf(s0[r], 0.125f, mh * (float)(j0 - i)) : -INFINITY;
      float v1 = (j1 <= i) ? fmaf(s1[r], 0.125f, mh * (float)(j1 - i)) : -INFINITY;
      float t = fmaxf(v0, v1);
#pragma unroll
      for (int off = 1; off < 16; off <<= 1)
        t = fmaxf(t, __shfl_xor(t, off, 64));
      const float mn = fmaxf(mrow[r], t);           // finite from iter 0 onward
      alpha[r] = __expf(mrow[r] - mn);              // iter0: exp(-inf)=0, acc is 0 anyway
      mrow[r] = mn;
      p0[r] = __expf(v0 - mn);
      p1[r] = __expf(v1 - mn);
      float rs = p0[r] + p1[r];
#pragma unroll
      for (int off = 1; off < 16; off <<= 1)
        rs += __shfl_xor(rs, off, 64);
      lrow[r] = lrow[r] * alpha[r] + rs;
    }

    __syncthreads();  // fence: prior-iter P reads done before overwrite (compiler fence too)
#pragma unroll
    for (int r = 0; r < 4; ++r) {
      Plds[wid][4 * lhi + r][llo]      = (bf16_t)p0[r];
      Plds[wid][4 * lhi + r][llo + 16] = (bf16_t)p1[r];
    }
#pragma unroll
    for (int f = 0; f < 4; ++f) {
      acc[f][0] *= alpha[0]; acc[f][1] *= alpha[1];
      acc[f][2] *= alpha[2]; acc[f][3] *= alpha[3];
    }
    __syncthreads();  // P visible / ordered

    // ---- PV: A = P (from LDS), B = V (kv-contiguous from vt) ----
    const bf16x8 pa = *(const bf16x8*)&Plds[wid][llo][8 * lhi];
#pragma unroll
    for (int f = 0; f < 4; ++f) {
      bf16x8 vb = *(const bf16x8*)(vbase + (size_t)(f * 16 + llo) * TT + kv0 + 8 * lhi);
      acc[f] = MFMA_16x16x32_BF16(pa, vb, acc[f]);
    }
  }

  // ---- epilogue: y = acc / l ----
#pragma unroll
  for (int f = 0; f < 4; ++f) {
#pragma unroll
    for (int r = 0; r < 4; ++r) {
      float yv = acc[f][r] / lrow[r];
      y[(size_t)(b * TT + q0 + 4 * lhi + r) * CC + h * HD + f * 16 + llo] = (bf16_t)yv;
    }
  }
}

// ---------------- launch ----------------
extern "C" void kernel_launch(void* const* d_in, const int* in_sizes, int n_in,
                              void* d_out, int out_size, void* d_ws, size_t ws_size,
                              hipStream_t stream) {
  const float* x       = (const float*)d_in[0];
  const float* Wq      = (const float*)d_in[1];
  const float* bq      = (const float*)d_in[2];
  const float* Wkv     = (const float*)d_in[3];
  const float* bkv     = (const float*)d_in[4];
  const float* Wp      = (const float*)d_in[5];
  const float* bp      = (const float*)d_in[6];
  const float* alibi_m = (const float*)d_in[7];
  float* out = (float*)d_out;

  char* w = (char*)d_ws;
  bf16_t* xb   = (bf16_t*)w; w += (size_t)MM * CC * 2;        // 16.78 MB (reused as yb)
  bf16_t* qkv  = (bf16_t*)w; w += (size_t)MM * C3 * 2;        // 50.33 MB
  bf16_t* btq  = (bf16_t*)w; w += (size_t)C3 * CC * 2;        //  6.29 MB
  bf16_t* wpt  = (bf16_t*)w; w += (size_t)CC * CC * 2;        //  2.10 MB
  bf16_t* vt   = (bf16_t*)w; w += (size_t)BB * CC * TT * 2;   // 16.78 MB
  float*  bcat = (float*)w;  w += (size_t)C3 * 4;             // 12 KB
  bf16_t* yb   = xb;  // xb dead after QKV GEMM -> alias

  dim3 tb(32, 8);
  cast_x_kernel<<<8192, 256, 0, stream>>>(x, xb, MM * CC / 4);
  transpose_cast_kernel<<<dim3(32, 32), tb, 0, stream>>>(Wq, btq, 1024, 1024);
  transpose_cast_kernel<<<dim3(64, 32), tb, 0, stream>>>(Wkv, btq + (size_t)1024 * 1024, 1024, 2048);
  transpose_cast_kernel<<<dim3(32, 32), tb, 0, stream>>>(Wp, wpt, 1024, 1024);
  concat_bias_kernel<<<12, 256, 0, stream>>>(bq, bkv, bcat);

  gemm_kernel<bf16_t><<<dim3(MM / 128, C3 / 128), 256, 0, stream>>>(
      xb, btq, qkv, bcat, MM, C3, CC);
  transpose_v_kernel<<<dim3(TT / 32, CC / 32, BB), tb, 0, stream>>>(qkv, vt);
  attn_kernel<<<dim3(TT / 64, HH, BB), 256, 0, stream>>>(qkv, vt, alibi_m, yb);
  gemm_kernel<float><<<dim3(MM / 128, CC / 128), 256, 0, stream>>>(
      yb, wpt, out, bp, MM, CC, CC);
}

// Round 2
// 272.325 us; speedup vs baseline: 2.1153x; 2.1153x over previous
//
#include <hip/hip_runtime.h>
#include <hip/hip_bf16.h>
#include <math.h>

typedef __bf16 bf16_t;
typedef bf16_t bf16x8 __attribute__((ext_vector_type(8)));
typedef bf16_t bf16x4 __attribute__((ext_vector_type(4)));
typedef float  f32x4  __attribute__((ext_vector_type(4)));

#define MFMA_16x16x32_BF16(a, b, c) __builtin_amdgcn_mfma_f32_16x16x32_bf16((a), (b), (c), 0, 0, 0)

static constexpr int BB = 4, TT = 2048, CC = 1024, HH = 16, HD = 64;
static constexpr int C3 = 3 * CC;   // 3072
static constexpr int MM = BB * TT;  // 8192 rows
static constexpr size_t SL = (size_t)BB * HH * TT * HD;  // elems per q/k/v slice

// ---------------- cast x (fp32) -> xb (bf16) ----------------
__global__ void cast_x_kernel(const float* __restrict__ x, bf16_t* __restrict__ xb, int n4) {
  int i = blockIdx.x * blockDim.x + threadIdx.x;
  if (i >= n4) return;
  float4 v = reinterpret_cast<const float4*>(x)[i];
  bf16x4 o;
  o[0] = (bf16_t)v.x; o[1] = (bf16_t)v.y; o[2] = (bf16_t)v.z; o[3] = (bf16_t)v.w;
  reinterpret_cast<bf16x4*>(xb)[i] = o;
}

// ------------- transpose+cast weights: in fp32 [R][Cn] -> out bf16 [Cn][R] -------------
__global__ void transpose_cast_kernel(const float* __restrict__ in, bf16_t* __restrict__ out,
                                      int R, int Cn) {
  __shared__ float tile[32][33];
  int c0 = blockIdx.x * 32, r0 = blockIdx.y * 32;
  int tx = threadIdx.x, ty = threadIdx.y;
#pragma unroll
  for (int i = 0; i < 4; ++i)
    tile[ty + 8 * i][tx] = in[(size_t)(r0 + ty + 8 * i) * Cn + c0 + tx];
  __syncthreads();
#pragma unroll
  for (int i = 0; i < 4; ++i)
    out[(size_t)(c0 + ty + 8 * i) * R + r0 + tx] = (bf16_t)tile[tx][ty + 8 * i];
}

// ------------- transpose vh [BH][T][64] -> vt [BH][64][T] (dense per-head) -------------
__global__ void transpose_v_kernel(const bf16_t* __restrict__ vh, bf16_t* __restrict__ vt) {
  __shared__ bf16_t tile[32][33];
  int t0 = blockIdx.x * 32, d0 = blockIdx.y * 32, bh = blockIdx.z;
  int tx = threadIdx.x, ty = threadIdx.y;
  const bf16_t* src = vh + (size_t)bh * TT * HD;
  bf16_t* dst = vt + (size_t)bh * HD * TT;
#pragma unroll
  for (int i = 0; i < 4; ++i)
    tile[ty + 8 * i][tx] = src[(size_t)(t0 + ty + 8 * i) * HD + d0 + tx];
  __syncthreads();
#pragma unroll
  for (int i = 0; i < 4; ++i)
    dst[(size_t)(d0 + ty + 8 * i) * TT + t0 + tx] = tile[tx][ty + 8 * i];
}

// ------------- concat biases [bq | bkv] -> bias_cat[3072] -------------
__global__ void concat_bias_kernel(const float* __restrict__ bq, const float* __restrict__ bkv,
                                   float* __restrict__ dst) {
  int i = blockIdx.x * 256 + threadIdx.x;
  if (i >= 3072) return;
  const float* p = (i < 1024) ? (bq + i) : (bkv + i - 1024);
  dst[i] = *p;
}

// ---------------- GEMM: C[M,N] = A[M,K] * Bt[N,K]^T + bias ----------------
// SPLIT=1: scatter cols into qkvh [3][B][H][T][64] bf16 (for the QKV GEMM)
__device__ inline void store_out(float* p, float v)  { *p = v; }
__device__ inline void store_out(bf16_t* p, float v) { *p = (bf16_t)v; }

template <int SPLIT, typename OutT>
__global__ __launch_bounds__(256) void gemm_kernel(
    const bf16_t* __restrict__ A, const bf16_t* __restrict__ Bt, OutT* __restrict__ C,
    const float* __restrict__ bias, int M, int N, int K) {
  __shared__ bf16_t As[128][40];  // +8 pad -> 2-way-only LDS conflicts
  __shared__ bf16_t Bs[128][40];
  const int tid = threadIdx.x;
  const int wid = tid >> 6, lane = tid & 63;
  const int lhi = lane >> 4, llo = lane & 15;
  const int wm = (wid >> 1) * 64, wn = (wid & 1) * 64;
  const int m0 = blockIdx.x * 128, n0 = blockIdx.y * 128;
  const int srow = tid >> 2, scol = (tid & 3) * 8;

  f32x4 acc[4][4] = {};
  const bf16_t* pa0 = A + (size_t)(m0 + srow) * K + scol;
  const bf16_t* pb0 = Bt + (size_t)(n0 + srow) * K + scol;

  for (int k0 = 0; k0 < K; k0 += 32) {
    __syncthreads();
    bf16x8 a0 = *(const bf16x8*)(pa0 + k0);
    bf16x8 a1 = *(const bf16x8*)(pa0 + (size_t)64 * K + k0);
    bf16x8 b0 = *(const bf16x8*)(pb0 + k0);
    bf16x8 b1 = *(const bf16x8*)(pb0 + (size_t)64 * K + k0);
    *(bf16x8*)&As[srow][scol]      = a0;
    *(bf16x8*)&As[srow + 64][scol] = a1;
    *(bf16x8*)&Bs[srow][scol]      = b0;
    *(bf16x8*)&Bs[srow + 64][scol] = b1;
    __syncthreads();
    bf16x8 af[4], bfr[4];
#pragma unroll
    for (int mi = 0; mi < 4; ++mi) af[mi] = *(const bf16x8*)&As[wm + mi * 16 + llo][8 * lhi];
#pragma unroll
    for (int ni = 0; ni < 4; ++ni) bfr[ni] = *(const bf16x8*)&Bs[wn + ni * 16 + llo][8 * lhi];
#pragma unroll
    for (int mi = 0; mi < 4; ++mi)
#pragma unroll
      for (int ni = 0; ni < 4; ++ni)
        acc[mi][ni] = MFMA_16x16x32_BF16(af[mi], bfr[ni], acc[mi][ni]);
  }

#pragma unroll
  for (int mi = 0; mi < 4; ++mi) {
#pragma unroll
    for (int ni = 0; ni < 4; ++ni) {
      const int row0 = m0 + wm + mi * 16 + 4 * lhi;
      const int col  = n0 + wn + ni * 16 + llo;
      const float bv = bias[col];
      if constexpr (SPLIT) {
        const int sel = col >> 10, rem = col & 1023;
        const int hh = rem >> 6, dd = rem & 63;
#pragma unroll
        for (int r = 0; r < 4; ++r) {
          const int row = row0 + r;
          const int bb = row >> 11, t = row & 2047;
          size_t addr = ((((size_t)sel * BB + bb) * HH + hh) * TT + t) * HD + dd;
          ((bf16_t*)C)[addr] = (bf16_t)(acc[mi][ni][r] + bv);
        }
      } else {
#pragma unroll
        for (int r = 0; r < 4; ++r)
          store_out(&C[(size_t)(row0 + r) * N + col], acc[mi][ni][r] + bv);
      }
    }
  }
}

// ---------------- flash attention with ALiBi, causal ----------------
// grid (8, H, B), 256 threads = 4 waves; block handles q-tiles {bx, 15-bx} (128 rows each)
// wave w owns 32 q rows (2 x 16-row fragments); KVBLK=64; NO barriers (per-wave P tile)
__global__ __launch_bounds__(256) void attn_kernel(
    const bf16_t* __restrict__ qh,   // [B][H][T][64]
    const bf16_t* __restrict__ kh,   // [B][H][T][64]
    const bf16_t* __restrict__ vt,   // [B][H][64][T]
    const float* __restrict__ alibi_m,
    bf16_t* __restrict__ y) {        // [B*T][CC]
  __shared__ bf16_t Plds[4][32][68];  // per-wave; pad->conflict-free scalar writes
  const int b = blockIdx.z, h = blockIdx.y;
  const int tid = threadIdx.x, wid = tid >> 6, lane = tid & 63;
  const int lhi = lane >> 4, llo = lane & 15;
  const float mh = alibi_m[h];
  const size_t bh = (size_t)(b * HH + h);
  const bf16_t* qbase = qh + bh * TT * HD;
  const bf16_t* kbase = kh + bh * TT * HD;
  const bf16_t* vbase = vt + bh * HD * TT;

#pragma unroll 1
  for (int half = 0; half < 2; ++half) {
    const int jt = half ? (15 - (int)blockIdx.x) : (int)blockIdx.x;
    const int q0 = jt * 128 + wid * 32;

    bf16x8 qf[2][2];
#pragma unroll
    for (int f = 0; f < 2; ++f)
#pragma unroll
      for (int kc = 0; kc < 2; ++kc)
        qf[f][kc] = *(const bf16x8*)(qbase + (size_t)(q0 + 16 * f + llo) * HD + 32 * kc + 8 * lhi);

    f32x4 acc[2][4] = {};
    float mrow[2][4], lrow[2][4];
#pragma unroll
    for (int f = 0; f < 2; ++f)
#pragma unroll
      for (int r = 0; r < 4; ++r) { mrow[f][r] = -INFINITY; lrow[f][r] = 0.f; }

    for (int kv0 = 0; kv0 < q0 + 32; kv0 += 64) {
      // ---- QK^T: s[frag][colchunk] over 64 kv ----
      f32x4 s[2][4] = {};
#pragma unroll
      for (int c = 0; c < 4; ++c) {
        const bf16_t* kp = kbase + (size_t)(kv0 + 16 * c + llo) * HD + 8 * lhi;
        bf16x8 k0 = *(const bf16x8*)kp;
        bf16x8 k1 = *(const bf16x8*)(kp + 32);
        s[0][c] = MFMA_16x16x32_BF16(qf[0][0], k0, s[0][c]);
        s[0][c] = MFMA_16x16x32_BF16(qf[0][1], k1, s[0][c]);
        s[1][c] = MFMA_16x16x32_BF16(qf[1][0], k0, s[1][c]);
        s[1][c] = MFMA_16x16x32_BF16(qf[1][1], k1, s[1][c]);
      }
      // ---- V fragment loads (independent of softmax; issue early) ----
      bf16x8 vv[4][2];
#pragma unroll
      for (int d = 0; d < 4; ++d) {
        const bf16_t* vp = vbase + (size_t)(16 * d + llo) * TT + kv0 + 8 * lhi;
        vv[d][0] = *(const bf16x8*)vp;
        vv[d][1] = *(const bf16x8*)(vp + 32);
      }
      // ---- online softmax (per-row regs; 16-lane shuffle reduce; ALiBi+causal) ----
      float alpha[2][4];
#pragma unroll
      for (int f = 0; f < 2; ++f) {
#pragma unroll
        for (int r = 0; r < 4; ++r) {
          const int i = q0 + 16 * f + 4 * lhi + r;
          float v[4];
#pragma unroll
          for (int c = 0; c < 4; ++c) {
            const int j = kv0 + 16 * c + llo;
            v[c] = (j <= i) ? fmaf(s[f][c][r], 0.125f, mh * (float)(j - i)) : -INFINITY;
          }
          float t = fmaxf(fmaxf(v[0], v[1]), fmaxf(v[2], v[3]));
#pragma unroll
          for (int off = 1; off < 16; off <<= 1) t = fmaxf(t, __shfl_xor(t, off, 64));
          const float mn = fmaxf(mrow[f][r], t);
          alpha[f][r] = __expf(mrow[f][r] - mn);
          mrow[f][r] = mn;
          float rs = 0.f;
#pragma unroll
          for (int c = 0; c < 4; ++c) {
            float p = __expf(v[c] - mn);
            Plds[wid][16 * f + 4 * lhi + r][16 * c + llo] = (bf16_t)p;
            rs += p;
          }
#pragma unroll
          for (int off = 1; off < 16; off <<= 1) rs += __shfl_xor(rs, off, 64);
          lrow[f][r] = lrow[f][r] * alpha[f][r] + rs;
        }
      }
      // ---- PV (P via per-wave LDS bounce; no barriers needed) ----
#pragma unroll
      for (int f = 0; f < 2; ++f) {
        bf16x8 pa0 = *(const bf16x8*)&Plds[wid][16 * f + llo][8 * lhi];
        bf16x8 pa1 = *(const bf16x8*)&Plds[wid][16 * f + llo][32 + 8 * lhi];
#pragma unroll
        for (int d = 0; d < 4; ++d) {
          f32x4 a = acc[f][d];
          a[0] *= alpha[f][0]; a[1] *= alpha[f][1];
          a[2] *= alpha[f][2]; a[3] *= alpha[f][3];
          a = MFMA_16x16x32_BF16(pa0, vv[d][0], a);
          a = MFMA_16x16x32_BF16(pa1, vv[d][1], a);
          acc[f][d] = a;
        }
      }
    }
    // ---- epilogue ----
#pragma unroll
    for (int f = 0; f < 2; ++f)
#pragma unroll
      for (int d = 0; d < 4; ++d)
#pragma unroll
        for (int r = 0; r < 4; ++r) {
          const int row = q0 + 16 * f + 4 * lhi + r;
          y[(size_t)(b * TT + row) * CC + h * HD + 16 * d + llo] =
              (bf16_t)(acc[f][d][r] / lrow[f][r]);
        }
  }
}

// ---------------- launch ----------------
extern "C" void kernel_launch(void* const* d_in, const int* in_sizes, int n_in,
                              void* d_out, int out_size, void* d_ws, size_t ws_size,
                              hipStream_t stream) {
  const float* x       = (const float*)d_in[0];
  const float* Wq      = (const float*)d_in[1];
  const float* bq      = (const float*)d_in[2];
  const float* Wkv     = (const float*)d_in[3];
  const float* bkv     = (const float*)d_in[4];
  const float* Wp      = (const float*)d_in[5];
  const float* bp      = (const float*)d_in[6];
  const float* alibi_m = (const float*)d_in[7];
  float* out = (float*)d_out;

  char* w = (char*)d_ws;
  bf16_t* xb   = (bf16_t*)w; w += (size_t)MM * CC * 2;        // 16.78 MB (reused as yb)
  bf16_t* qkvh = (bf16_t*)w; w += SL * 3 * 2;                 // 50.33 MB  [3][B][H][T][64]
  bf16_t* btq  = (bf16_t*)w; w += (size_t)C3 * CC * 2;        //  6.29 MB
  bf16_t* wpt  = (bf16_t*)w; w += (size_t)CC * CC * 2;        //  2.10 MB
  bf16_t* vtb  = (bf16_t*)w; w += SL * 2;                     // 16.78 MB  [B][H][64][T]
  float*  bcat = (float*)w;  w += (size_t)C3 * 4;             // 12 KB
  bf16_t* yb   = xb;  // xb dead after QKV GEMM -> alias

  dim3 tb(32, 8);
  cast_x_kernel<<<8192, 256, 0, stream>>>(x, xb, MM * CC / 4);
  transpose_cast_kernel<<<dim3(32, 32), tb, 0, stream>>>(Wq, btq, 1024, 1024);
  transpose_cast_kernel<<<dim3(64, 32), tb, 0, stream>>>(Wkv, btq + (size_t)1024 * 1024, 1024, 2048);
  transpose_cast_kernel<<<dim3(32, 32), tb, 0, stream>>>(Wp, wpt, 1024, 1024);
  concat_bias_kernel<<<12, 256, 0, stream>>>(bq, bkv, bcat);

  gemm_kernel<1, bf16_t><<<dim3(MM / 128, C3 / 128), 256, 0, stream>>>(
      xb, btq, qkvh, bcat, MM, C3, CC);
  transpose_v_kernel<<<dim3(TT / 32, HD / 32, BB * HH), tb, 0, stream>>>(qkvh + 2 * SL, vtb);
  attn_kernel<<<dim3(8, HH, BB), 256, 0, stream>>>(qkvh, qkvh + SL, vtb, alibi_m, yb);
  gemm_kernel<0, float><<<dim3(MM / 128, CC / 128), 256, 0, stream>>>(
      yb, wpt, out, bp, MM, CC, CC);
}